// Round 4
// baseline (493.499 us; speedup 1.0000x reference)
//
#include <hip/hip_runtime.h>

typedef _Float16 half8 __attribute__((ext_vector_type(8)));
typedef _Float16 half4 __attribute__((ext_vector_type(4)));
typedef __fp16  fp16x2 __attribute__((ext_vector_type(2)));
typedef float floatx4 __attribute__((ext_vector_type(4)));

#define TPB 256

struct GAddr { int i00, i10, i01, i11; float wx, wy; };

__device__ __forceinline__ GAddr gaddr(int res, float u, float v) {
    float r = (float)res;
    float sx = u * r, sy = v * r;
    int x0 = (int)sx, y0 = (int)sy;            // truncation, matches astype(int32)
    float wx = sx - (float)x0, wy = sy - (float)y0;
    int x1 = min(x0 + 1, res), y1 = min(y0 + 1, res);
    GAddr g;
    g.i00 = y0 * res + x0;  g.i10 = y0 * res + x1;   // reference stride = res
    g.i01 = y1 * res + x0;  g.i11 = y1 * res + x1;
    g.wx = wx; g.wy = wy;
    return g;
}

__device__ __forceinline__ void bil4(float4 v00, float4 v10, float4 v01, float4 v11,
                                     float wx, float wy, float* f) {
    float omx = 1.0f - wx, omy = 1.0f - wy;
    f[0] = (v00.x * omx + v10.x * wx) * omy + (v01.x * omx + v11.x * wx) * wy;
    f[1] = (v00.y * omx + v10.y * wx) * omy + (v01.y * omx + v11.y * wx) * wy;
    f[2] = (v00.z * omx + v10.z * wx) * omy + (v01.z * omx + v11.z * wx) * wy;
    f[3] = (v00.w * omx + v10.w * wx) * omy + (v01.w * omx + v11.w * wx) * wy;
}

// Per-wave fused MFMA pipeline, 64 points/wave/iter, no __syncthreads.
// Software-pipelined: next tile's x + emb0/emb1 gathers are issued mid-iter so
// their latency overlaps layer-1..3 MFMA of the current tile. emb2 (4.6 KB,
// L1-resident) is gathered synchronously.
__global__ __launch_bounds__(TPB, 4) void dgn_mfma(
    const float*  __restrict__ x,
    const float4* __restrict__ emb0,
    const float4* __restrict__ emb1,
    const float4* __restrict__ emb2,
    const float*  __restrict__ w1, const float* __restrict__ b1,
    const float*  __restrict__ w2, const float* __restrict__ b2,
    const float*  __restrict__ w3, const float* __restrict__ b3,
    float*        __restrict__ out, int npts)
{
    __shared__ __align__(16) _Float16 smem[4 * 4096];   // 4 waves * 8KB, wave-private

    const int tid  = threadIdx.x;
    const int lane = tid & 63;
    const int wv   = tid >> 6;
    const int l15  = lane & 15;
    const int quad = lane >> 4;

    // ---- persistent weight fragments (identical to validated round-2) ----
    half8 w1f[4];
    #pragma unroll
    for (int nt = 0; nt < 4; ++nt)
        #pragma unroll
        for (int j = 0; j < 8; ++j) {
            int k = quad * 8 + j;
            w1f[nt][j] = (k < 13) ? (_Float16)w1[k * 64 + nt * 16 + l15] : (_Float16)0.0f;
        }
    float b1v[4], b2v[4];
    #pragma unroll
    for (int nt = 0; nt < 4; ++nt) { b1v[nt] = b1[nt * 16 + l15]; b2v[nt] = b2[nt * 16 + l15]; }
    half8 w2f[4][2];
    #pragma unroll
    for (int nt = 0; nt < 4; ++nt)
        #pragma unroll
        for (int ks = 0; ks < 2; ++ks)
            #pragma unroll
            for (int j = 0; j < 8; ++j) {
                int s  = ks * 32 + quad * 8 + j;
                int oh = ((s & 3) << 4) | (s >> 2);     // sigma^{-1}
                w2f[nt][ks][j] = (_Float16)w2[oh * 64 + nt * 16 + l15];
            }
    half8 w3f[2];
    #pragma unroll
    for (int ks = 0; ks < 2; ++ks)
        #pragma unroll
        for (int j = 0; j < 8; ++j) {
            int s  = ks * 32 + quad * 8 + j;
            int oh = ((s & 3) << 4) | (s >> 2);
            w3f[ks][j] = (l15 < 3) ? (_Float16)w3[oh * 3 + l15] : (_Float16)0.0f;
        }
    const float qsel = (quad == 0) ? 1.0f : 0.0f;
    const float qb30 = qsel * b3[0], qb31 = qsel * b3[1], qb32 = qsel * b3[2];

    // ---- precomputed LDS addresses (half-element units). All mt terms are
    // +mt*1024 immediates because mt*16 == 0 (mod 8) leaves the swizzle fixed.
    const int bufh = wv * 4096;
    const int ewr0 = bufh + lane * 64 + ((lane & 7) ^ 0) * 8;
    const int ewr1 = bufh + lane * 64 + ((lane & 7) ^ 1) * 8;
    const int erd  = bufh + l15 * 64 + (quad ^ (l15 & 7)) * 8;          // quad<2 only
    int hwb[4];
    #pragma unroll
    for (int r = 0; r < 4; ++r) {
        int pr = quad * 4 + r;
        hwb[r] = bufh + pr * 64 + (((l15 >> 1) ^ (pr & 7)) * 8) + (l15 & 1) * 4;
    }
    int rd2[2];
    #pragma unroll
    for (int ks = 0; ks < 2; ++ks)
        rd2[ks] = bufh + l15 * 64 + (((ks * 4 + quad) ^ (l15 & 7)) * 8);

    const int ntiles = npts >> 8;
    const int gdim   = gridDim.x;

    // ---- prologue: tile-0 x + emb0/emb1 gathers in flight ----
    float cidf, cu, cv, wx0, wy0, wx1, wy1;
    float4 t00, t01, t02, t03, t10, t11, t12, t13;
    {
        int p0 = (blockIdx.x << 8) + (wv << 6) + lane;
        cidf = x[3 * p0]; cu = x[3 * p0 + 1]; cv = x[3 * p0 + 2];
        GAddr g0 = gaddr(512, cu, cv); wx0 = g0.wx; wy0 = g0.wy;
        t00 = emb0[g0.i00]; t01 = emb0[g0.i10]; t02 = emb0[g0.i01]; t03 = emb0[g0.i11];
        GAddr g1 = gaddr(264, cu, cv); wx1 = g1.wx; wy1 = g1.wy;
        t10 = emb1[g1.i00]; t11 = emb1[g1.i10]; t12 = emb1[g1.i01]; t13 = emb1[g1.i11];
    }

    for (int tile = blockIdx.x; tile < ntiles; tile += gdim) {
        // ---- finish current tile's features ----
        float f[12];
        bil4(t00, t01, t02, t03, wx0, wy0, f);
        bil4(t10, t11, t12, t13, wx1, wy1, f + 4);
        {
            GAddr g2 = gaddr(16, cu, cv);
            bil4(emb2[g2.i00], emb2[g2.i10], emb2[g2.i01], emb2[g2.i11], g2.wx, g2.wy, f + 8);
        }
        // E pack (pkrtz; features O(1e-4), idf O(1) -> negligible vs threshold)
        union H8 { half8 v; fp16x2 p[4]; } e0u, e1u;
        e0u.p[0] = __builtin_amdgcn_cvt_pkrtz(cidf, f[0]);
        e0u.p[1] = __builtin_amdgcn_cvt_pkrtz(f[1], f[2]);
        e0u.p[2] = __builtin_amdgcn_cvt_pkrtz(f[3], f[4]);
        e0u.p[3] = __builtin_amdgcn_cvt_pkrtz(f[5], f[6]);
        e1u.p[0] = __builtin_amdgcn_cvt_pkrtz(f[7], f[8]);
        e1u.p[1] = __builtin_amdgcn_cvt_pkrtz(f[9], f[10]);
        e1u.p[2] = __builtin_amdgcn_cvt_pkrtz(f[11], 0.0f);
        e1u.p[3] = __builtin_amdgcn_cvt_pkrtz(0.0f, 0.0f);
        *(half8*)&smem[ewr0] = e0u.v;
        *(half8*)&smem[ewr1] = e1u.v;

        // ---- prefetch next tile's x (latency hidden by layer 1) ----
        int nxt = tile + gdim;
        int ptn = (((nxt < ntiles) ? nxt : tile) << 8) + (wv << 6) + lane;
        float nidf = x[3 * ptn], nu = x[3 * ptn + 1], nv = x[3 * ptn + 2];

        // ---- layer 1: K=32 (quads 2-3 feed zeros), bias in C-init ----
        #pragma unroll
        for (int mt = 0; mt < 4; ++mt) {
            half8 ea = { (_Float16)0, (_Float16)0, (_Float16)0, (_Float16)0,
                         (_Float16)0, (_Float16)0, (_Float16)0, (_Float16)0 };
            if (quad < 2) ea = *(const half8*)&smem[erd + mt * 1024];
            floatx4 acc[4];
            #pragma unroll
            for (int nt = 0; nt < 4; ++nt) {
                acc[nt] = (floatx4){ b1v[nt], b1v[nt], b1v[nt], b1v[nt] };
                acc[nt] = __builtin_amdgcn_mfma_f32_16x16x32_f16(ea, w1f[nt], acc[nt], 0, 0, 0);
            }
            #pragma unroll
            for (int r = 0; r < 4; ++r) {
                half4 hv = { (_Float16)fmaxf(acc[0][r], 0.0f),
                             (_Float16)fmaxf(acc[1][r], 0.0f),
                             (_Float16)fmaxf(acc[2][r], 0.0f),
                             (_Float16)fmaxf(acc[3][r], 0.0f) };
                *(half4*)&smem[hwb[r] + mt * 1024] = hv;
            }
        }

        // ---- issue next tile's emb0/emb1 gathers (hidden by layers 2-3) ----
        float nwx0, nwy0, nwx1, nwy1;
        float4 n00, n01, n02, n03, n10, n11, n12, n13;
        {
            GAddr g0 = gaddr(512, nu, nv); nwx0 = g0.wx; nwy0 = g0.wy;
            n00 = emb0[g0.i00]; n01 = emb0[g0.i10]; n02 = emb0[g0.i01]; n03 = emb0[g0.i11];
            GAddr g1 = gaddr(264, nu, nv); nwx1 = g1.wx; nwy1 = g1.wy;
            n10 = emb1[g1.i00]; n11 = emb1[g1.i10]; n12 = emb1[g1.i01]; n13 = emb1[g1.i11];
        }

        // ---- layer 2 (K=64) + layer 3 (transposed), per m-tile ----
        #pragma unroll
        for (int mt = 0; mt < 4; ++mt) {
            floatx4 acc[4];
            #pragma unroll
            for (int nt = 0; nt < 4; ++nt)
                acc[nt] = (floatx4){ b2v[nt], b2v[nt], b2v[nt], b2v[nt] };
            #pragma unroll
            for (int ks = 0; ks < 2; ++ks) {
                half8 a2 = *(const half8*)&smem[rd2[ks] + mt * 1024];
                #pragma unroll
                for (int nt = 0; nt < 4; ++nt)
                    acc[nt] = __builtin_amdgcn_mfma_f32_16x16x32_f16(a2, w2f[nt][ks], acc[nt], 0, 0, 0);
            }
            #pragma unroll
            for (int r = 0; r < 4; ++r) {
                half4 hv = { (_Float16)fmaxf(acc[0][r], 0.0f),
                             (_Float16)fmaxf(acc[1][r], 0.0f),
                             (_Float16)fmaxf(acc[2][r], 0.0f),
                             (_Float16)fmaxf(acc[3][r], 0.0f) };
                *(half4*)&smem[hwb[r] + mt * 1024] = hv;
            }
            floatx4 acc3 = (floatx4){ qb30, qb31, qb32, 0.0f };
            #pragma unroll
            for (int ks = 0; ks < 2; ++ks) {
                half8 bfr = *(const half8*)&smem[rd2[ks] + mt * 1024];
                acc3 = __builtin_amdgcn_mfma_f32_16x16x32_f16(w3f[ks], bfr, acc3, 0, 0, 0);
            }
            if (quad == 0) {
                const int P = (tile << 8) + (wv << 6) + mt * 16 + l15;
                out[3 * P + 0] = acc3[0];
                out[3 * P + 1] = acc3[1];
                out[3 * P + 2] = acc3[2];
            }
        }

        // ---- rotate pipeline registers ----
        cidf = nidf; cu = nu; cv = nv;
        wx0 = nwx0; wy0 = nwy0; wx1 = nwx1; wy1 = nwy1;
        t00 = n00; t01 = n01; t02 = n02; t03 = n03;
        t10 = n10; t11 = n11; t12 = n12; t13 = n13;
    }
}

extern "C" void kernel_launch(void* const* d_in, const int* in_sizes, int n_in,
                              void* d_out, int out_size, void* d_ws, size_t ws_size,
                              hipStream_t stream) {
    const float*  x    = (const float*)  d_in[0];
    const float4* emb0 = (const float4*) d_in[1];
    const float4* emb1 = (const float4*) d_in[2];
    const float4* emb2 = (const float4*) d_in[3];
    const float*  w1   = (const float*)  d_in[4];
    const float*  b1   = (const float*)  d_in[5];
    const float*  w2   = (const float*)  d_in[6];
    const float*  b2   = (const float*)  d_in[7];
    const float*  w3   = (const float*)  d_in[8];
    const float*  b3   = (const float*)  d_in[9];
    float* out = (float*)d_out;

    int npts = in_sizes[0] / 3;
    int grid = 1024;                                    // 4 blocks/CU resident
    dgn_mfma<<<grid, TPB, 0, stream>>>(x, emb0, emb1, emb2,
                                       w1, b1, w2, b2, w3, b3, out, npts);
}

// Round 5
// 277.075 us; speedup vs baseline: 1.7811x; 1.7811x over previous
//
#include <hip/hip_runtime.h>

typedef _Float16 half8 __attribute__((ext_vector_type(8)));
typedef _Float16 half4 __attribute__((ext_vector_type(4)));
typedef __fp16  fp16x2 __attribute__((ext_vector_type(2)));
typedef float floatx4 __attribute__((ext_vector_type(4)));

#define TPB 256

struct GAddr { int i00, i10, i01, i11; float wx, wy; };

__device__ __forceinline__ GAddr gaddr(int res, float u, float v) {
    float r = (float)res;
    float sx = u * r, sy = v * r;
    int x0 = (int)sx, y0 = (int)sy;            // truncation, matches astype(int32)
    float wx = sx - (float)x0, wy = sy - (float)y0;
    int x1 = min(x0 + 1, res), y1 = min(y0 + 1, res);
    GAddr g;
    g.i00 = y0 * res + x0;  g.i10 = y0 * res + x1;   // reference stride = res
    g.i01 = y1 * res + x0;  g.i11 = y1 * res + x1;
    g.wx = wx; g.wy = wy;
    return g;
}

__device__ __forceinline__ void bil4(float4 v00, float4 v10, float4 v01, float4 v11,
                                     float wx, float wy, float* f) {
    float omx = 1.0f - wx, omy = 1.0f - wy;
    f[0] = (v00.x * omx + v10.x * wx) * omy + (v01.x * omx + v11.x * wx) * wy;
    f[1] = (v00.y * omx + v10.y * wx) * omy + (v01.y * omx + v11.y * wx) * wy;
    f[2] = (v00.z * omx + v10.z * wx) * omy + (v01.z * omx + v11.z * wx) * wy;
    f[3] = (v00.w * omx + v10.w * wx) * omy + (v01.w * omx + v11.w * wx) * wy;
}

// relu (f32) then packed f32->f16 convert: 4 v_max + 2 v_cvt_pkrtz.
__device__ __forceinline__ half4 relu_pk4(float a, float b, float c, float d) {
    union { half4 v; fp16x2 p[2]; } u;
    u.p[0] = __builtin_amdgcn_cvt_pkrtz(fmaxf(a, 0.0f), fmaxf(b, 0.0f));
    u.p[1] = __builtin_amdgcn_cvt_pkrtz(fmaxf(c, 0.0f), fmaxf(d, 0.0f));
    return u.v;
}

// Per-wave fused MFMA pipeline, 64 points/wave/iter, no __syncthreads.
// Software-pipelined: next tile's x + emb0/emb1 gathers issued mid-iter so
// their latency overlaps layers 1-3 of the current tile. emb2 (4.6 KB,
// L1-resident) stays synchronous.
// __launch_bounds__(256,2): 256-reg budget -> the pipeline registers
// (32 prefetch + 56 weight-frag VGPRs) fit WITHOUT scratch spill (round-4's
// (256,4) forced 128 regs and spilled ~900 MB/dispatch to scratch).
__global__ __launch_bounds__(TPB, 2) void dgn_mfma(
    const float*  __restrict__ x,
    const float4* __restrict__ emb0,
    const float4* __restrict__ emb1,
    const float4* __restrict__ emb2,
    const float*  __restrict__ w1, const float* __restrict__ b1,
    const float*  __restrict__ w2, const float* __restrict__ b2,
    const float*  __restrict__ w3, const float* __restrict__ b3,
    float*        __restrict__ out, int npts)
{
    __shared__ __align__(16) _Float16 smem[4 * 4096];   // 4 waves * 8KB, wave-private

    const int tid  = threadIdx.x;
    const int lane = tid & 63;
    const int wv   = tid >> 6;
    const int l15  = lane & 15;
    const int quad = lane >> 4;

    // ---- persistent weight fragments (identical to validated round-2) ----
    half8 w1f[4];
    #pragma unroll
    for (int nt = 0; nt < 4; ++nt)
        #pragma unroll
        for (int j = 0; j < 8; ++j) {
            int k = quad * 8 + j;
            w1f[nt][j] = (k < 13) ? (_Float16)w1[k * 64 + nt * 16 + l15] : (_Float16)0.0f;
        }
    float b1v[4], b2v[4];
    #pragma unroll
    for (int nt = 0; nt < 4; ++nt) { b1v[nt] = b1[nt * 16 + l15]; b2v[nt] = b2[nt * 16 + l15]; }
    half8 w2f[4][2];
    #pragma unroll
    for (int nt = 0; nt < 4; ++nt)
        #pragma unroll
        for (int ks = 0; ks < 2; ++ks)
            #pragma unroll
            for (int j = 0; j < 8; ++j) {
                int s  = ks * 32 + quad * 8 + j;
                int oh = ((s & 3) << 4) | (s >> 2);     // sigma^{-1}
                w2f[nt][ks][j] = (_Float16)w2[oh * 64 + nt * 16 + l15];
            }
    half8 w3f[2];
    #pragma unroll
    for (int ks = 0; ks < 2; ++ks)
        #pragma unroll
        for (int j = 0; j < 8; ++j) {
            int s  = ks * 32 + quad * 8 + j;
            int oh = ((s & 3) << 4) | (s >> 2);
            w3f[ks][j] = (l15 < 3) ? (_Float16)w3[oh * 3 + l15] : (_Float16)0.0f;
        }
    const float qsel = (quad == 0) ? 1.0f : 0.0f;
    const float qb30 = qsel * b3[0], qb31 = qsel * b3[1], qb32 = qsel * b3[2];

    // ---- precomputed LDS addresses (half-element units). mt terms are
    // +mt*1024 immediates because mt*16 == 0 (mod 8) leaves the swizzle fixed.
    const int bufh = wv * 4096;
    const int ewr0 = bufh + lane * 64 + ((lane & 7) ^ 0) * 8;
    const int ewr1 = bufh + lane * 64 + ((lane & 7) ^ 1) * 8;
    const int erd  = bufh + l15 * 64 + (quad ^ (l15 & 7)) * 8;          // quad<2 only
    int hwb[4];
    #pragma unroll
    for (int r = 0; r < 4; ++r) {
        int pr = quad * 4 + r;
        hwb[r] = bufh + pr * 64 + (((l15 >> 1) ^ (pr & 7)) * 8) + (l15 & 1) * 4;
    }
    int rd2[2];
    #pragma unroll
    for (int ks = 0; ks < 2; ++ks)
        rd2[ks] = bufh + l15 * 64 + (((ks * 4 + quad) ^ (l15 & 7)) * 8);

    const int ntiles = npts >> 8;
    const int gdim   = gridDim.x;

    // ---- prologue: tile-0 x + emb0/emb1 gathers in flight ----
    float cidf, cu, cv, wx0, wy0, wx1, wy1;
    float4 t00, t01, t02, t03, t10, t11, t12, t13;
    {
        int p0 = (blockIdx.x << 8) + (wv << 6) + lane;
        cidf = x[3 * p0]; cu = x[3 * p0 + 1]; cv = x[3 * p0 + 2];
        GAddr g0 = gaddr(512, cu, cv); wx0 = g0.wx; wy0 = g0.wy;
        t00 = emb0[g0.i00]; t01 = emb0[g0.i10]; t02 = emb0[g0.i01]; t03 = emb0[g0.i11];
        GAddr g1 = gaddr(264, cu, cv); wx1 = g1.wx; wy1 = g1.wy;
        t10 = emb1[g1.i00]; t11 = emb1[g1.i10]; t12 = emb1[g1.i01]; t13 = emb1[g1.i11];
    }

    for (int tile = blockIdx.x; tile < ntiles; tile += gdim) {
        // ---- finish current tile's features ----
        float f[12];
        bil4(t00, t01, t02, t03, wx0, wy0, f);
        bil4(t10, t11, t12, t13, wx1, wy1, f + 4);
        {
            GAddr g2 = gaddr(16, cu, cv);
            bil4(emb2[g2.i00], emb2[g2.i10], emb2[g2.i01], emb2[g2.i11], g2.wx, g2.wy, f + 8);
        }
        // E pack (pkrtz; features O(1e-4), idf O(1) -> negligible vs threshold)
        union H8 { half8 v; fp16x2 p[4]; } e0u, e1u;
        e0u.p[0] = __builtin_amdgcn_cvt_pkrtz(cidf, f[0]);
        e0u.p[1] = __builtin_amdgcn_cvt_pkrtz(f[1], f[2]);
        e0u.p[2] = __builtin_amdgcn_cvt_pkrtz(f[3], f[4]);
        e0u.p[3] = __builtin_amdgcn_cvt_pkrtz(f[5], f[6]);
        e1u.p[0] = __builtin_amdgcn_cvt_pkrtz(f[7], f[8]);
        e1u.p[1] = __builtin_amdgcn_cvt_pkrtz(f[9], f[10]);
        e1u.p[2] = __builtin_amdgcn_cvt_pkrtz(f[11], 0.0f);
        e1u.p[3] = __builtin_amdgcn_cvt_pkrtz(0.0f, 0.0f);
        *(half8*)&smem[ewr0] = e0u.v;
        *(half8*)&smem[ewr1] = e1u.v;

        // ---- prefetch next tile's x (latency hidden by layer 1) ----
        int nxt = tile + gdim;
        int ptn = (((nxt < ntiles) ? nxt : tile) << 8) + (wv << 6) + lane;
        float nidf = x[3 * ptn], nu = x[3 * ptn + 1], nv = x[3 * ptn + 2];

        // ---- layer 1: K=32 (quads 2-3 feed zeros), bias in C-init ----
        #pragma unroll
        for (int mt = 0; mt < 4; ++mt) {
            half8 ea = { (_Float16)0, (_Float16)0, (_Float16)0, (_Float16)0,
                         (_Float16)0, (_Float16)0, (_Float16)0, (_Float16)0 };
            if (quad < 2) ea = *(const half8*)&smem[erd + mt * 1024];
            floatx4 acc[4];
            #pragma unroll
            for (int nt = 0; nt < 4; ++nt) {
                acc[nt] = (floatx4){ b1v[nt], b1v[nt], b1v[nt], b1v[nt] };
                acc[nt] = __builtin_amdgcn_mfma_f32_16x16x32_f16(ea, w1f[nt], acc[nt], 0, 0, 0);
            }
            #pragma unroll
            for (int r = 0; r < 4; ++r)
                *(half4*)&smem[hwb[r] + mt * 1024] =
                    relu_pk4(acc[0][r], acc[1][r], acc[2][r], acc[3][r]);
        }

        // ---- issue next tile's emb0/emb1 gathers (hidden by layers 2-3) ----
        float nwx0, nwy0, nwx1, nwy1;
        float4 n00, n01, n02, n03, n10, n11, n12, n13;
        {
            GAddr g0 = gaddr(512, nu, nv); nwx0 = g0.wx; nwy0 = g0.wy;
            n00 = emb0[g0.i00]; n01 = emb0[g0.i10]; n02 = emb0[g0.i01]; n03 = emb0[g0.i11];
            GAddr g1 = gaddr(264, nu, nv); nwx1 = g1.wx; nwy1 = g1.wy;
            n10 = emb1[g1.i00]; n11 = emb1[g1.i10]; n12 = emb1[g1.i01]; n13 = emb1[g1.i11];
        }

        // ---- layer 2 (K=64), h2 overwrites h1 rows of the SAME mt only ----
        #pragma unroll
        for (int mt = 0; mt < 4; ++mt) {
            floatx4 acc[4];
            #pragma unroll
            for (int nt = 0; nt < 4; ++nt)
                acc[nt] = (floatx4){ b2v[nt], b2v[nt], b2v[nt], b2v[nt] };
            #pragma unroll
            for (int ks = 0; ks < 2; ++ks) {
                half8 a2 = *(const half8*)&smem[rd2[ks] + mt * 1024];
                #pragma unroll
                for (int nt = 0; nt < 4; ++nt)
                    acc[nt] = __builtin_amdgcn_mfma_f32_16x16x32_f16(a2, w2f[nt][ks], acc[nt], 0, 0, 0);
            }
            #pragma unroll
            for (int r = 0; r < 4; ++r)
                *(half4*)&smem[hwb[r] + mt * 1024] =
                    relu_pk4(acc[0][r], acc[1][r], acc[2][r], acc[3][r]);
        }

        // ---- layer 3 (transposed) in a separate mt loop: the h2-write ->
        // layer-3-read LDS round-trip stalls once, not 4x. ----
        #pragma unroll
        for (int mt = 0; mt < 4; ++mt) {
            floatx4 acc3 = (floatx4){ qb30, qb31, qb32, 0.0f };
            #pragma unroll
            for (int ks = 0; ks < 2; ++ks) {
                half8 bfr = *(const half8*)&smem[rd2[ks] + mt * 1024];
                acc3 = __builtin_amdgcn_mfma_f32_16x16x32_f16(w3f[ks], bfr, acc3, 0, 0, 0);
            }
            if (quad == 0) {
                const int P = (tile << 8) + (wv << 6) + mt * 16 + l15;
                out[3 * P + 0] = acc3[0];
                out[3 * P + 1] = acc3[1];
                out[3 * P + 2] = acc3[2];
            }
        }

        // ---- rotate pipeline registers ----
        cidf = nidf; cu = nu; cv = nv;
        wx0 = nwx0; wy0 = nwy0; wx1 = nwx1; wy1 = nwy1;
        t00 = n00; t01 = n01; t02 = n02; t03 = n03;
        t10 = n10; t11 = n11; t12 = n12; t13 = n13;
    }
}

extern "C" void kernel_launch(void* const* d_in, const int* in_sizes, int n_in,
                              void* d_out, int out_size, void* d_ws, size_t ws_size,
                              hipStream_t stream) {
    const float*  x    = (const float*)  d_in[0];
    const float4* emb0 = (const float4*) d_in[1];
    const float4* emb1 = (const float4*) d_in[2];
    const float4* emb2 = (const float4*) d_in[3];
    const float*  w1   = (const float*)  d_in[4];
    const float*  b1   = (const float*)  d_in[5];
    const float*  w2   = (const float*)  d_in[6];
    const float*  b2   = (const float*)  d_in[7];
    const float*  w3   = (const float*)  d_in[8];
    const float*  b3   = (const float*)  d_in[9];
    float* out = (float*)d_out;

    int npts = in_sizes[0] / 3;
    int grid = 512;                                     // 2 blocks/CU resident
    dgn_mfma<<<grid, TPB, 0, stream>>>(x, emb0, emb1, emb2,
                                       w1, b1, w2, b2, w3, b3, out, npts);
}